// Round 14
// baseline (618.491 us; speedup 1.0000x reference)
//
#include <hip/hip_runtime.h>
#include <stdint.h>
#include <math.h>

typedef __bf16 bf16;
typedef __attribute__((ext_vector_type(8))) __bf16 bf16x8;
typedef __attribute__((ext_vector_type(4))) __bf16 bf16x4;
typedef __attribute__((ext_vector_type(4))) float f32x4;
typedef unsigned short u16;
typedef unsigned int u32;

// ---- constants for this problem ----
#define BATCH 4
#define SEQ   2048
#define EMB   1024
#define HEADS 16
#define HDIM  64
#define BH    (BATCH*HEADS)      // 64

// softmax scale folded into Q: 1/sqrt(64). Scores in NATURAL-log domain.
#define QSCALE 0.125f

// ws layout (bytes)
#define OFF_XB 0u                        // bf16 [8192][1024]
#define OFF_WC 16777216u                 // bf16 [3072][1024]
#define OFF_Q  23068672u                 // bf16 [64][2048][64]
#define OFF_K  39845888u                 // bf16 [64][2048][64]
#define OFF_VT 56623104u                 // bf16 [64][64][2048]

// Explicit vmcnt drain before barriers (staged global_load_lds tile landed).
#define DRAIN_VM asm volatile("s_waitcnt vmcnt(0)" ::: "memory")
// Within-wave LDS RAW fence: ds_write completion before following ds_read.
#define FENCE_LDS do { \
    asm volatile("s_waitcnt lgkmcnt(0)" ::: "memory"); \
    __builtin_amdgcn_sched_barrier(0); \
} while (0)

// RULE (R4-R6 + R10): on the softmax exp path, BOTH the transcendental
// producer AND its first consumer must be compiler-visible. __expf + scalar
// (__bf16) casts only. No inline asm on this path.
// RULE (R12): keep attn grid at 512 blocks (8 blocks/bh = L2-resident K/V).

__device__ __forceinline__ u16 f2bf(float f) {
    u32 b = __builtin_bit_cast(u32, f);
    return (u16)((b + 0x7fffu + ((b >> 16) & 1u)) >> 16);
}

// ---------------- fp32 -> bf16 convert, all 4 arrays in one launch ----------------
__global__ void cvt_all(const float* __restrict__ x,
                        const float* __restrict__ wq, const float* __restrict__ wk,
                        const float* __restrict__ wv,
                        u16* __restrict__ xb, u16* __restrict__ wc) {
    const int X4 = (BATCH * SEQ * EMB) / 4;   // 2097152
    const int W4 = (EMB * EMB) / 4;           // 262144
    const int n4 = X4 + 3 * W4;
    int stride = gridDim.x * blockDim.x;
    for (int i = blockIdx.x * blockDim.x + threadIdx.x; i < n4; i += stride) {
        const float* src; u16* dst; int j;
        if (i < X4)              { src = x;  dst = xb;                j = i; }
        else if (i < X4 + W4)    { src = wq; dst = wc;                j = i - X4; }
        else if (i < X4 + 2*W4)  { src = wk; dst = wc + EMB * EMB;    j = i - X4 - W4; }
        else                     { src = wv; dst = wc + 2 * EMB * EMB; j = i - X4 - 2 * W4; }
        float4 v = reinterpret_cast<const float4*>(src)[j];
        ushort4 o;
        o.x = f2bf(v.x); o.y = f2bf(v.y); o.z = f2bf(v.z); o.w = f2bf(v.w);
        reinterpret_cast<ushort4*>(dst)[j] = o;
    }
}

// ---------------- fused QKV GEMM (unchanged; 1.14 PF, shape-matched) ----------------
__global__ __launch_bounds__(256, 3) void qkv_gemm(
    const u16* __restrict__ xb, const u16* __restrict__ wc,
    const float* __restrict__ bq, const float* __restrict__ bk_, const float* __restrict__ bv,
    u16* __restrict__ Qw, u16* __restrict__ Kw, u16* __restrict__ Vt)
{
    __shared__ u16 lds[2 * 128 * 64];
    const int tid = threadIdx.x;
    const int w = tid >> 6, l = tid & 63;
    const int hi = l >> 4, lo = l & 15;
    const int bm = blockIdx.x & 63;
    const int bn = blockIdx.x >> 6;
    const int wm = w >> 1, wn = w & 1;

    const int srow   = l >> 3;
    const int schunk = (l & 7) ^ (srow & 7);

    f32x4 acc[4][4];
#pragma unroll
    for (int i = 0; i < 4; ++i)
#pragma unroll
        for (int j = 0; j < 4; ++j) acc[i][j] = f32x4{0.f, 0.f, 0.f, 0.f};

    for (int t = 0; t < 16; ++t) {
        const u16* asrc = xb + (size_t)(bm * 128 + srow) * 1024 + t * 64 + schunk * 8;
        const u16* bsrc = wc + (size_t)(bn * 128 + srow) * 1024 + t * 64 + schunk * 8;
#pragma unroll
        for (int i = 0; i < 4; ++i) {
            int c = i * 4 + w;
            __builtin_amdgcn_global_load_lds(
                (const __attribute__((address_space(1))) u32*)(asrc + (size_t)c * 8 * 1024),
                (__attribute__((address_space(3))) u32*)(&lds[c * 512]), 16, 0, 0);
            __builtin_amdgcn_global_load_lds(
                (const __attribute__((address_space(1))) u32*)(bsrc + (size_t)c * 8 * 1024),
                (__attribute__((address_space(3))) u32*)(&lds[128 * 64 + c * 512]), 16, 0, 0);
        }
        DRAIN_VM;
        __syncthreads();
#pragma unroll
        for (int kk = 0; kk < 2; ++kk) {
            bf16x8 af[4], bfr[4];
#pragma unroll
            for (int mt = 0; mt < 4; ++mt) {
                int row = wm * 64 + mt * 16 + lo;
                int off = (kk * 64 + hi * 16) ^ ((row & 7) << 4);
                af[mt] = *reinterpret_cast<const bf16x8*>((const char*)lds + row * 128 + off);
            }
#pragma unroll
            for (int nt = 0; nt < 4; ++nt) {
                int row = wn * 64 + nt * 16 + lo;
                int off = (kk * 64 + hi * 16) ^ ((row & 7) << 4);
                bfr[nt] = *reinterpret_cast<const bf16x8*>((const char*)lds + 128 * 64 * 2 + row * 128 + off);
            }
#pragma unroll
            for (int mt = 0; mt < 4; ++mt)
#pragma unroll
                for (int nt = 0; nt < 4; ++nt)
                    acc[mt][nt] = __builtin_amdgcn_mfma_f32_16x16x32_bf16(af[mt], bfr[nt], acc[mt][nt], 0, 0, 0);
        }
        __syncthreads();
    }

#pragma unroll
    for (int nt = 0; nt < 4; ++nt) {
        int ng  = bn * 128 + wn * 64 + nt * 16 + lo;
        int mat = ng >> 10;
        int nl  = ng & 1023;
        int h = nl >> 6, d = nl & 63;
        const float* bp = (mat == 0) ? bq : (mat == 1 ? bk_ : bv);
        float bias = bp[nl];
        float scl = (mat == 0) ? QSCALE : 1.0f;
#pragma unroll
        for (int mt = 0; mt < 4; ++mt) {
            int mbase = bm * 128 + wm * 64 + mt * 16 + hi * 4;
            int b = mbase >> 11, s = mbase & 2047;
            if (mat < 2) {
                u16* dst = (mat == 0) ? Qw : Kw;
                size_t base = ((size_t)(b * 16 + h) * 2048) * 64 + (size_t)d;
#pragma unroll
                for (int r = 0; r < 4; ++r)
                    dst[base + (size_t)(s + r) * 64] = f2bf((acc[mt][nt][r] + bias) * scl);
            } else {
                ushort4 o;
                o.x = f2bf(acc[mt][nt][0] + bias);
                o.y = f2bf(acc[mt][nt][1] + bias);
                o.z = f2bf(acc[mt][nt][2] + bias);
                o.w = f2bf(acc[mt][nt][3] + bias);
                *reinterpret_cast<ushort4*>(&Vt[((size_t)(b * 16 + h) * 64 + d) * 2048 + s]) = o;
            }
        }
    }
}

// ---------------- flash attention v14: kv-split, 16-wave blocks, 32 waves/CU ----------------
// 512 blocks x 1024 threads: 8 q-groups x 2 kv-halves, 256 q/block, KVB=64.
// kv-split compute path identical to the correctness-proven R12 kernel; grid
// stays 512 (R12's FETCH-doubling fixed) and the split's low VGPR count (52
// measured in R12) allows 8 waves/SIMD -> 32 waves/CU (2x R13's hiding).
// LDS: 32KB K/V dbuf + 16 x 2560B P (80B-stride rows) = 73.7KB -> 2 blocks/CU.
// Pair-combine epilogue in two half-steps to fit the LDS scratch.
#define KVB 64
__global__ __launch_bounds__(1024, 8) void attn(
    const u16* __restrict__ Qw, const u16* __restrict__ Kw, const u16* __restrict__ Vt,
    float* __restrict__ out)
{
    __shared__ char smem[73728];   // 2 bufs x (K 8KB | V 8KB) + 16 waves x 2560B P
    const int tid = threadIdx.x;
    const int w = tid >> 6, l = tid & 63;
    const int hi = l >> 4, lo = l & 15;
    const int h2 = w & 1;          // kv-half this wave owns
    const int qg = w >> 1;         // q-group (0..7)

    // XCD-aware remap: XCD (bid&7) owns bh in [8x, 8x+8) -> K/V set = 4MB = one L2
    const int bid = blockIdx.x;
    const int xcd = bid & 7, ii = bid >> 3;   // ii: 0..63
    const int bh = xcd * 8 + (ii & 7);
    const int qt = ii >> 3;                   // 0..7
    const int bb = bh >> 4, h = bh & 15;
    const int q0w = qt * 256 + qg * 32;       // wave's first q row

    const u16* Qb = Qw + ((size_t)bh * 2048 + q0w) * 64;
    const u16* Kb = Kw + (size_t)bh * 2048 * 64;
    const u16* Vb = Vt + (size_t)bh * 64 * 2048;
    char* bufs = smem;                      // buf b at b*16384: K at +0, V at +8192
    char* myP  = smem + 32768 + w * 2560;   // [32 q][80B] (wave's 32-kv half at [0,64))

    // Q fragments: qf[qsub][kc] = Q[q0w + qsub*16 + lo][kc*32 + hi*8 ..+8]
    bf16x8 qf[2][2];
#pragma unroll
    for (int qs = 0; qs < 2; ++qs)
#pragma unroll
        for (int kc = 0; kc < 2; ++kc)
            qf[qs][kc] = *reinterpret_cast<const bf16x8*>(Qb + (qs * 16 + lo) * 64 + kc * 32 + hi * 8);

    // all-ones A-fragment for the denominator MFMA
    bf16x8 ones;
#pragma unroll
    for (int i = 0; i < 8; ++i) ones[i] = (__bf16)1.0f;

    // staging: 16 waves, 1 gload each. Waves 0-7 stage K rows, 8-15 stage V rows.
    // wave covers LDS rows r0 = (w&7)*8 + (l>>3), 16B chunk l&7; source chunk
    // XOR-swizzled so LDS[r][c] = G[r][c ^ (r&7)]
    const int isK = (w < 8);
    const int r0 = (w & 7) * 8 + (l >> 3);
    const int cs = (l & 7) ^ (r0 & 7);

    const f32x4 zf = {0.f, 0.f, 0.f, 0.f};
    f32x4 acc[4][2];
#pragma unroll
    for (int dt = 0; dt < 4; ++dt)
#pragma unroll
        for (int qs = 0; qs < 2; ++qs) acc[dt][qs] = zf;
    f32x4 den[2] = {zf, zf};

#define STAGE(kvbase, dst)                                                              \
    {                                                                                   \
        if (isK) {                                                                      \
            const u16* srcK = Kb + (size_t)((kvbase) + r0) * 64 + cs * 8;               \
            __builtin_amdgcn_global_load_lds(                                           \
                (const __attribute__((address_space(1))) u32*)srcK,                     \
                (__attribute__((address_space(3))) u32*)((dst) + (w & 7) * 1024),       \
                16, 0, 0);                                                              \
        } else {                                                                        \
            const u16* srcV = Vb + (size_t)r0 * 2048 + (kvbase) + cs * 8;               \
            __builtin_amdgcn_global_load_lds(                                           \
                (const __attribute__((address_space(1))) u32*)srcV,                     \
                (__attribute__((address_space(3))) u32*)((dst) + 8192 + (w & 7) * 1024),\
                16, 0, 0);                                                              \
        }                                                                               \
    }

    STAGE(0, bufs);
    DRAIN_VM;
    __syncthreads();

    int buf = 0;
    for (int t = 0; t < 2048 / KVB; ++t) {
        if (t + 1 < 2048 / KVB) STAGE((t + 1) * KVB, bufs + (buf ^ 1) * 16384);

        const char* bK = bufs + buf * 16384;
        const char* bV = bK + 8192;

        // QK^T on this wave's kv-half: st[ct][qs];
        // lane holds S[kv = h2*32 + ct*16 + hi*4 + r][q = qs*16 + lo]
        f32x4 st[2][2];
        __builtin_amdgcn_s_setprio(1);
#pragma unroll
        for (int ct = 0; ct < 2; ++ct) {
            int r = h2 * 32 + ct * 16 + lo;
            bf16x8 k0 = *reinterpret_cast<const bf16x8*>(bK + r * 128 + ((hi ^ (lo & 7)) * 16));
            bf16x8 k1 = *reinterpret_cast<const bf16x8*>(bK + r * 128 + (((4 + hi) ^ (lo & 7)) * 16));
#pragma unroll
            for (int qs = 0; qs < 2; ++qs) {
                f32x4 s4 = __builtin_amdgcn_mfma_f32_16x16x32_bf16(k0, qf[qs][0], zf, 0, 0, 0);
                st[ct][qs] = __builtin_amdgcn_mfma_f32_16x16x32_bf16(k1, qf[qs][1], s4, 0, 0, 0);
            }
        }
        __builtin_amdgcn_s_setprio(0);
        // P = exp(S) -> bf16 via compiler-visible scalar casts; one 8B LDS store.
        // P row holds this wave's 32 kv at bytes [0,64); row stride 80B.
#pragma unroll
        for (int ct = 0; ct < 2; ++ct)
#pragma unroll
            for (int qs = 0; qs < 2; ++qs) {
                bf16x4 pb;
#pragma unroll
                for (int r = 0; r < 4; ++r) pb[r] = (__bf16)__expf(st[ct][qs][r]);
                *reinterpret_cast<bf16x4*>(myP + (qs * 16 + lo) * 80 + ct * 32 + hi * 8) = pb;
            }
        FENCE_LDS;   // P writes complete before P fragment reads
        // PV over this wave's kv-half: B-frag pf covers kv_local = hi*8..+7
        bf16x8 pf[2];
#pragma unroll
        for (int qs = 0; qs < 2; ++qs)
            pf[qs] = *reinterpret_cast<const bf16x8*>(myP + (qs * 16 + lo) * 80 + hi * 16);
        __builtin_amdgcn_s_setprio(1);
#pragma unroll
        for (int qs = 0; qs < 2; ++qs)
            den[qs] = __builtin_amdgcn_mfma_f32_16x16x32_bf16(ones, pf[qs], den[qs], 0, 0, 0);
#pragma unroll
        for (int dt = 0; dt < 4; ++dt) {
            int r = dt * 16 + lo;
            bf16x8 vf = *reinterpret_cast<const bf16x8*>(
                bV + r * 128 + (((h2 * 4 + hi) ^ (lo & 7)) * 16));
#pragma unroll
            for (int qs = 0; qs < 2; ++qs)
                acc[dt][qs] = __builtin_amdgcn_mfma_f32_16x16x32_bf16(vf, pf[qs], acc[dt][qs], 0, 0, 0);
        }
        __builtin_amdgcn_s_setprio(0);
        DRAIN_VM;          // staged next tile fully landed in LDS
        __syncthreads();   // all waves done reading buf
        buf ^= 1;
    }
#undef STAGE

    // ---- pair combine, two half-steps (scratch 8 pairs x 8704B = 69.6KB <= 73.7KB):
    // odd waves (h2=1) dump acc+den; even waves combine, normalize, store all.
    float* scr = reinterpret_cast<float*>(smem);
    if (h2) {
        float* my = scr + qg * 2176 + l * 34;   // 34 floats: 32 acc + 2 den
#pragma unroll
        for (int dt = 0; dt < 4; ++dt)
#pragma unroll
            for (int qs = 0; qs < 2; ++qs)
#pragma unroll
                for (int r = 0; r < 4; ++r)
                    my[dt * 8 + qs * 4 + r] = acc[dt][qs][r];
        my[32] = den[0][0];
        my[33] = den[1][0];
    }
    asm volatile("s_waitcnt lgkmcnt(0)" ::: "memory");
    __syncthreads();
    if (!h2) {
        const float* pr = scr + qg * 2176 + l * 34;
        float inv[2];
        inv[0] = 1.f / (den[0][0] + pr[32]);
        inv[1] = 1.f / (den[1][0] + pr[33]);
        // lane holds O[d = dt*16 + hi*4 + r][q = qs*16 + lo]
#pragma unroll
        for (int dt = 0; dt < 4; ++dt)
#pragma unroll
            for (int qs = 0; qs < 2; ++qs) {
                f32x4 v = acc[dt][qs];
#pragma unroll
                for (int r = 0; r < 4; ++r) v[r] += pr[dt * 8 + qs * 4 + r];
                float* og = out + ((size_t)(bb * 2048 + q0w + qs * 16 + lo)) * 1024 + h * 64 + dt * 16 + hi * 4;
                float2 v01 = {v[0] * inv[qs], v[1] * inv[qs]};
                float2 v23 = {v[2] * inv[qs], v[3] * inv[qs]};
                *reinterpret_cast<float2*>(og)     = v01;
                *reinterpret_cast<float2*>(og + 2) = v23;
            }
    }
}

extern "C" void kernel_launch(void* const* d_in, const int* in_sizes, int n_in,
                              void* d_out, int out_size, void* d_ws, size_t ws_size,
                              hipStream_t stream) {
    (void)in_sizes; (void)n_in; (void)out_size; (void)ws_size;
    const float* x  = (const float*)d_in[0];
    const float* Wq = (const float*)d_in[1];
    const float* bq = (const float*)d_in[2];
    const float* Wk = (const float*)d_in[3];
    const float* bk = (const float*)d_in[4];
    const float* Wv = (const float*)d_in[5];
    const float* bv = (const float*)d_in[6];
    float* out = (float*)d_out;
    char* ws = (char*)d_ws;

    u16* xb = (u16*)(ws + OFF_XB);
    u16* wc = (u16*)(ws + OFF_WC);
    u16* Qw = (u16*)(ws + OFF_Q);
    u16* Kw = (u16*)(ws + OFF_K);
    u16* Vt = (u16*)(ws + OFF_VT);

    cvt_all<<<2048, 256, 0, stream>>>(x, Wq, Wk, Wv, xb, wc);
    qkv_gemm<<<64 * 24, 256, 0, stream>>>(xb, wc, bq, bk, bv, Qw, Kw, Vt);
    attn<<<512, 1024, 0, stream>>>(Qw, Kw, Vt, out);
}

// Round 15
// 141.074 us; speedup vs baseline: 4.3842x; 4.3842x over previous
//
#include <hip/hip_runtime.h>
#include <stdint.h>
#include <math.h>

typedef __bf16 bf16;
typedef __attribute__((ext_vector_type(8))) __bf16 bf16x8;
typedef __attribute__((ext_vector_type(4))) __bf16 bf16x4;
typedef __attribute__((ext_vector_type(4))) float f32x4;
typedef unsigned short u16;
typedef unsigned int u32;

// ---- constants for this problem ----
#define BATCH 4
#define SEQ   2048
#define EMB   1024
#define HEADS 16
#define HDIM  64
#define BH    (BATCH*HEADS)      // 64

// softmax scale folded into Q: 1/sqrt(64). Scores in NATURAL-log domain.
#define QSCALE 0.125f

// ws layout (bytes)
#define OFF_XB 0u                        // bf16 [8192][1024]
#define OFF_WC 16777216u                 // bf16 [3072][1024]
#define OFF_Q  23068672u                 // bf16 [64][2048][64]
#define OFF_K  39845888u                 // bf16 [64][2048][64]
#define OFF_VT 56623104u                 // bf16 [64][64][2048]

// Explicit vmcnt drain before barriers (staged global_load_lds tile landed).
#define DRAIN_VM asm volatile("s_waitcnt vmcnt(0)" ::: "memory")
// Within-wave LDS RAW fence: ds_write completion before following ds_read.
#define FENCE_LDS do { \
    asm volatile("s_waitcnt lgkmcnt(0)" ::: "memory"); \
    __builtin_amdgcn_sched_barrier(0); \
} while (0)

// SESSION RULES (hard-won):
// 1 (R4-R6+R10): on the softmax exp path, BOTH the transcendental producer AND
//   its first consumer must be compiler-visible. __expf + scalar (__bf16)
//   casts only; no inline asm touching TRANS results (hazard wait-states).
// 2 (R12): keep attn grid at 512 blocks (8 blocks/bh = per-XCD L2-resident
//   K/V) and don't shrink per-wave-per-tile MFMA work.
// 3 (R14): __launch_bounds__ waves/EU is a VGPR-budget contract: live state
//   over 512/waves_per_EU VGPRs => accumulator spill to scratch (558us).

__device__ __forceinline__ u16 f2bf(float f) {
    u32 b = __builtin_bit_cast(u32, f);
    return (u16)((b + 0x7fffu + ((b >> 16) & 1u)) >> 16);
}

// ---------------- fp32 -> bf16 convert, all 4 arrays in one launch ----------------
__global__ void cvt_all(const float* __restrict__ x,
                        const float* __restrict__ wq, const float* __restrict__ wk,
                        const float* __restrict__ wv,
                        u16* __restrict__ xb, u16* __restrict__ wc) {
    const int X4 = (BATCH * SEQ * EMB) / 4;   // 2097152
    const int W4 = (EMB * EMB) / 4;           // 262144
    const int n4 = X4 + 3 * W4;
    int stride = gridDim.x * blockDim.x;
    for (int i = blockIdx.x * blockDim.x + threadIdx.x; i < n4; i += stride) {
        const float* src; u16* dst; int j;
        if (i < X4)              { src = x;  dst = xb;                j = i; }
        else if (i < X4 + W4)    { src = wq; dst = wc;                j = i - X4; }
        else if (i < X4 + 2*W4)  { src = wk; dst = wc + EMB * EMB;    j = i - X4 - W4; }
        else                     { src = wv; dst = wc + 2 * EMB * EMB; j = i - X4 - 2 * W4; }
        float4 v = reinterpret_cast<const float4*>(src)[j];
        ushort4 o;
        o.x = f2bf(v.x); o.y = f2bf(v.y); o.z = f2bf(v.z); o.w = f2bf(v.w);
        reinterpret_cast<ushort4*>(dst)[j] = o;
    }
}

// ---------------- fused QKV GEMM (1.14 PF, shape-matched) ----------------
__global__ __launch_bounds__(256, 3) void qkv_gemm(
    const u16* __restrict__ xb, const u16* __restrict__ wc,
    const float* __restrict__ bq, const float* __restrict__ bk_, const float* __restrict__ bv,
    u16* __restrict__ Qw, u16* __restrict__ Kw, u16* __restrict__ Vt)
{
    __shared__ u16 lds[2 * 128 * 64];
    const int tid = threadIdx.x;
    const int w = tid >> 6, l = tid & 63;
    const int hi = l >> 4, lo = l & 15;
    const int bm = blockIdx.x & 63;
    const int bn = blockIdx.x >> 6;
    const int wm = w >> 1, wn = w & 1;

    const int srow   = l >> 3;
    const int schunk = (l & 7) ^ (srow & 7);

    f32x4 acc[4][4];
#pragma unroll
    for (int i = 0; i < 4; ++i)
#pragma unroll
        for (int j = 0; j < 4; ++j) acc[i][j] = f32x4{0.f, 0.f, 0.f, 0.f};

    for (int t = 0; t < 16; ++t) {
        const u16* asrc = xb + (size_t)(bm * 128 + srow) * 1024 + t * 64 + schunk * 8;
        const u16* bsrc = wc + (size_t)(bn * 128 + srow) * 1024 + t * 64 + schunk * 8;
#pragma unroll
        for (int i = 0; i < 4; ++i) {
            int c = i * 4 + w;
            __builtin_amdgcn_global_load_lds(
                (const __attribute__((address_space(1))) u32*)(asrc + (size_t)c * 8 * 1024),
                (__attribute__((address_space(3))) u32*)(&lds[c * 512]), 16, 0, 0);
            __builtin_amdgcn_global_load_lds(
                (const __attribute__((address_space(1))) u32*)(bsrc + (size_t)c * 8 * 1024),
                (__attribute__((address_space(3))) u32*)(&lds[128 * 64 + c * 512]), 16, 0, 0);
        }
        DRAIN_VM;
        __syncthreads();
#pragma unroll
        for (int kk = 0; kk < 2; ++kk) {
            bf16x8 af[4], bfr[4];
#pragma unroll
            for (int mt = 0; mt < 4; ++mt) {
                int row = wm * 64 + mt * 16 + lo;
                int off = (kk * 64 + hi * 16) ^ ((row & 7) << 4);
                af[mt] = *reinterpret_cast<const bf16x8*>((const char*)lds + row * 128 + off);
            }
#pragma unroll
            for (int nt = 0; nt < 4; ++nt) {
                int row = wn * 64 + nt * 16 + lo;
                int off = (kk * 64 + hi * 16) ^ ((row & 7) << 4);
                bfr[nt] = *reinterpret_cast<const bf16x8*>((const char*)lds + 128 * 64 * 2 + row * 128 + off);
            }
#pragma unroll
            for (int mt = 0; mt < 4; ++mt)
#pragma unroll
                for (int nt = 0; nt < 4; ++nt)
                    acc[mt][nt] = __builtin_amdgcn_mfma_f32_16x16x32_bf16(af[mt], bfr[nt], acc[mt][nt], 0, 0, 0);
        }
        __syncthreads();
    }

#pragma unroll
    for (int nt = 0; nt < 4; ++nt) {
        int ng  = bn * 128 + wn * 64 + nt * 16 + lo;
        int mat = ng >> 10;
        int nl  = ng & 1023;
        int h = nl >> 6, d = nl & 63;
        const float* bp = (mat == 0) ? bq : (mat == 1 ? bk_ : bv);
        float bias = bp[nl];
        float scl = (mat == 0) ? QSCALE : 1.0f;
#pragma unroll
        for (int mt = 0; mt < 4; ++mt) {
            int mbase = bm * 128 + wm * 64 + mt * 16 + hi * 4;
            int b = mbase >> 11, s = mbase & 2047;
            if (mat < 2) {
                u16* dst = (mat == 0) ? Qw : Kw;
                size_t base = ((size_t)(b * 16 + h) * 2048) * 64 + (size_t)d;
#pragma unroll
                for (int r = 0; r < 4; ++r)
                    dst[base + (size_t)(s + r) * 64] = f2bf((acc[mt][nt][r] + bias) * scl);
            } else {
                ushort4 o;
                o.x = f2bf(acc[mt][nt][0] + bias);
                o.y = f2bf(acc[mt][nt][1] + bias);
                o.z = f2bf(acc[mt][nt][2] + bias);
                o.w = f2bf(acc[mt][nt][3] + bias);
                *reinterpret_cast<ushort4*>(&Vt[((size_t)(b * 16 + h) * 64 + d) * 2048 + s]) = o;
            }
        }
    }
}

// ---------------- flash attention (R13, best verified: 83 us) ----------------
// 8 waves/block, 256 q/block, 512 blocks (2/CU, 8 blocks/bh -> L2-resident K/V).
// Double-buffered K/V staging via global_load_lds; ones-MFMA denominator;
// fully compiler-visible exp path; setprio around MFMA clusters.
#define KVB 64
__global__ __launch_bounds__(512, 4) void attn(
    const u16* __restrict__ Qw, const u16* __restrict__ Kw, const u16* __restrict__ Vt,
    float* __restrict__ out)
{
    __shared__ char smem[69632];   // 2 bufs x (K 8KB | V 8KB) + 8 waves x 4608B P
    const int tid = threadIdx.x;
    const int w = tid >> 6, l = tid & 63;
    const int hi = l >> 4, lo = l & 15;

    // XCD-aware remap: XCD (bid&7) owns bh in [8x, 8x+8) -> K/V set = 4MB = one L2
    const int bid = blockIdx.x;
    const int xcd = bid & 7, ii = bid >> 3;
    const int bh = xcd * 8 + (ii & 7);
    const int qt = ii >> 3;               // 0..7
    const int bb = bh >> 4, h = bh & 15;
    const int q0w = qt * 256 + w * 32;    // wave's first q row

    const u16* Qb = Qw + ((size_t)bh * 2048 + q0w) * 64;
    const u16* Kb = Kw + (size_t)bh * 2048 * 64;
    const u16* Vb = Vt + (size_t)bh * 64 * 2048;
    char* bufs = smem;                      // buf b at b*16384: K at +0, V at +8192
    char* myP  = smem + 32768 + w * 4608;   // [32 q][144B]

    // Q fragments: qf[qsub][kc] = Q[q0w + qsub*16 + lo][kc*32 + hi*8 ..+8]
    bf16x8 qf[2][2];
#pragma unroll
    for (int qs = 0; qs < 2; ++qs)
#pragma unroll
        for (int kc = 0; kc < 2; ++kc)
            qf[qs][kc] = *reinterpret_cast<const bf16x8*>(Qb + (qs * 16 + lo) * 64 + kc * 32 + hi * 8);

    // all-ones A-fragment for the denominator MFMA
    bf16x8 ones;
#pragma unroll
    for (int i = 0; i < 8; ++i) ones[i] = (__bf16)1.0f;

    // staging: 8 waves cover 64 rows; wave w, lane l -> row r0 = w*8 + (l>>3),
    // chunk l&7; source chunk XOR-swizzled so LDS[r][c] = G[r][c ^ (r&7)]
    const int r0 = w * 8 + (l >> 3);
    const int cs = (l & 7) ^ (r0 & 7);

    const f32x4 zf = {0.f, 0.f, 0.f, 0.f};
    f32x4 acc[4][2];
#pragma unroll
    for (int dt = 0; dt < 4; ++dt)
#pragma unroll
        for (int qs = 0; qs < 2; ++qs) acc[dt][qs] = zf;
    f32x4 den[2] = {zf, zf};

#define STAGE(kvbase, dst)                                                          \
    {                                                                               \
        const u16* srcK = Kb + (size_t)((kvbase) + r0) * 64 + cs * 8;               \
        __builtin_amdgcn_global_load_lds(                                           \
            (const __attribute__((address_space(1))) u32*)srcK,                     \
            (__attribute__((address_space(3))) u32*)((dst) + w * 1024), 16, 0, 0);  \
        const u16* srcV = Vb + (size_t)r0 * 2048 + (kvbase) + cs * 8;               \
        __builtin_amdgcn_global_load_lds(                                           \
            (const __attribute__((address_space(1))) u32*)srcV,                     \
            (__attribute__((address_space(3))) u32*)((dst) + 8192 + w * 1024),      \
            16, 0, 0);                                                              \
    }

    STAGE(0, bufs);
    DRAIN_VM;
    __syncthreads();

    int buf = 0;
    for (int t = 0; t < 2048 / KVB; ++t) {
        if (t + 1 < 2048 / KVB) STAGE((t + 1) * KVB, bufs + (buf ^ 1) * 16384);

        const char* bK = bufs + buf * 16384;
        const char* bV = bK + 8192;

        // QK^T: st[ct][qs]; lane holds S[kv=ct*16+hi*4+r][q=qs*16+lo]
        f32x4 st[4][2];
        __builtin_amdgcn_s_setprio(1);
#pragma unroll
        for (int ct = 0; ct < 4; ++ct) {
            int r = ct * 16 + lo;
            bf16x8 k0 = *reinterpret_cast<const bf16x8*>(bK + r * 128 + ((hi ^ (r & 7)) * 16));
            bf16x8 k1 = *reinterpret_cast<const bf16x8*>(bK + r * 128 + (((4 + hi) ^ (r & 7)) * 16));
#pragma unroll
            for (int qs = 0; qs < 2; ++qs) {
                f32x4 s4 = __builtin_amdgcn_mfma_f32_16x16x32_bf16(k0, qf[qs][0], zf, 0, 0, 0);
                st[ct][qs] = __builtin_amdgcn_mfma_f32_16x16x32_bf16(k1, qf[qs][1], s4, 0, 0, 0);
            }
        }
        __builtin_amdgcn_s_setprio(0);
        // P = exp(S) -> bf16 via compiler-visible scalar casts; one 8B LDS store
#pragma unroll
        for (int ct = 0; ct < 4; ++ct)
#pragma unroll
            for (int qs = 0; qs < 2; ++qs) {
                bf16x4 pb;
#pragma unroll
                for (int r = 0; r < 4; ++r) pb[r] = (__bf16)__expf(st[ct][qs][r]);
                *reinterpret_cast<bf16x4*>(myP + (qs * 16 + lo) * 144 + ct * 32 + hi * 8) = pb;
            }
        FENCE_LDS;   // P writes complete before P fragment reads
        // PV: B-frag from P, A-frag V^T from LDS; +ones-MFMA for denominator
        __builtin_amdgcn_s_setprio(1);
#pragma unroll
        for (int hf = 0; hf < 2; ++hf) {
            bf16x8 pf[2];
#pragma unroll
            for (int qs = 0; qs < 2; ++qs)
                pf[qs] = *reinterpret_cast<const bf16x8*>(myP + (qs * 16 + lo) * 144 + hf * 64 + hi * 16);
#pragma unroll
            for (int qs = 0; qs < 2; ++qs)
                den[qs] = __builtin_amdgcn_mfma_f32_16x16x32_bf16(ones, pf[qs], den[qs], 0, 0, 0);
#pragma unroll
            for (int dt = 0; dt < 4; ++dt) {
                int r = dt * 16 + lo;
                bf16x8 vf = *reinterpret_cast<const bf16x8*>(
                    bV + r * 128 + (((hf * 4 + hi) ^ (r & 7)) * 16));
#pragma unroll
                for (int qs = 0; qs < 2; ++qs)
                    acc[dt][qs] = __builtin_amdgcn_mfma_f32_16x16x32_bf16(vf, pf[qs], acc[dt][qs], 0, 0, 0);
            }
        }
        __builtin_amdgcn_s_setprio(0);
        DRAIN_VM;          // staged next tile fully landed in LDS
        __syncthreads();   // all waves done reading buf
        buf ^= 1;
    }
#undef STAGE

    // denominators: every reg of den[qs] equals den(q=lo) -- no cross-lane ops
    float inv[2];
#pragma unroll
    for (int qs = 0; qs < 2; ++qs) inv[qs] = 1.f / den[qs][0];

    // epilogue: direct scattered float2 stores; lane holds O[d=dt*16+hi*4+r][q=qs*16+lo].
#pragma unroll
    for (int dt = 0; dt < 4; ++dt)
#pragma unroll
        for (int qs = 0; qs < 2; ++qs) {
            float* og = out + ((size_t)(bb * 2048 + q0w + qs * 16 + lo)) * 1024 + h * 64 + dt * 16 + hi * 4;
            float2 v01 = {acc[dt][qs][0] * inv[qs], acc[dt][qs][1] * inv[qs]};
            float2 v23 = {acc[dt][qs][2] * inv[qs], acc[dt][qs][3] * inv[qs]};
            *reinterpret_cast<float2*>(og)     = v01;
            *reinterpret_cast<float2*>(og + 2) = v23;
        }
}

extern "C" void kernel_launch(void* const* d_in, const int* in_sizes, int n_in,
                              void* d_out, int out_size, void* d_ws, size_t ws_size,
                              hipStream_t stream) {
    (void)in_sizes; (void)n_in; (void)out_size; (void)ws_size;
    const float* x  = (const float*)d_in[0];
    const float* Wq = (const float*)d_in[1];
    const float* bq = (const float*)d_in[2];
    const float* Wk = (const float*)d_in[3];
    const float* bk = (const float*)d_in[4];
    const float* Wv = (const float*)d_in[5];
    const float* bv = (const float*)d_in[6];
    float* out = (float*)d_out;
    char* ws = (char*)d_ws;

    u16* xb = (u16*)(ws + OFF_XB);
    u16* wc = (u16*)(ws + OFF_WC);
    u16* Qw = (u16*)(ws + OFF_Q);
    u16* Kw = (u16*)(ws + OFF_K);
    u16* Vt = (u16*)(ws + OFF_VT);

    cvt_all<<<2048, 256, 0, stream>>>(x, Wq, Wk, Wv, xb, wc);
    qkv_gemm<<<64 * 24, 256, 0, stream>>>(xb, wc, bq, bk, bv, Qw, Kw, Vt);
    attn<<<512, 512, 0, stream>>>(Qw, Kw, Vt, out);
}